// Round 18
// baseline (807.415 us; speedup 1.0000x reference)
//
#include <hip/hip_runtime.h>
#include <hip/hip_bf16.h>

typedef __attribute__((ext_vector_type(4))) float f32x4;
typedef __attribute__((ext_vector_type(8))) short short8;
typedef __attribute__((ext_vector_type(4))) short short4_t;

#define LTOK 64
#define CDIM 256
#define FRS 576            // padded frag stride (shorts): 72 blocks x 8

static __device__ __forceinline__ short f2bf(float f) {
    __hip_bfloat16 h = __float2bfloat16(f);
    union { __hip_bfloat16 b; short s; } u; u.b = h;
    return u.s;
}
static __device__ __forceinline__ float bf2f(short s) {
    union { unsigned u; float f; } v;
    v.u = ((unsigned)(unsigned short)s) << 16;
    return v.f;
}
static __device__ __forceinline__ int KL(int l) { return l + (l >> 3); }

// ---------------- merged prep kernel ----------------
__global__ void prep_all(const float* __restrict__ qw, const float* __restrict__ pw,
                         const float* __restrict__ w1, const float* __restrict__ b1,
                         const float* __restrict__ w2, const float* __restrict__ b2,
                         const float* __restrict__ lsc,
                         short* __restrict__ wqs, short* __restrict__ wps,
                         float* __restrict__ biasT, float* __restrict__ scT) {
    if (blockIdx.x == 768) {
        int t = threadIdx.x;
        if (t < 8) scT[t] = expf(fminf(lsc[t], logf(100.0f)));
        if (t < 127) {
            float delta = (float)(t - 63);
            float sg = (delta > 0.f) ? 1.f : ((delta < 0.f) ? -1.f : 0.f);
            float r = sg * log1pf(fabsf(delta));
            float acc[8];
            #pragma unroll
            for (int q = 0; q < 8; ++q) acc[q] = b2[q];
            for (int m = 0; m < 384; ++m) {
                float hid = fmaxf(fmaf(r, w1[m * 2 + 1], b1[m]), 0.f);
                #pragma unroll
                for (int q = 0; q < 8; ++q) acc[q] = fmaf(hid, w2[q * 384 + m], acc[q]);
            }
            #pragma unroll
            for (int q = 0; q < 8; ++q) biasT[q * 127 + t] = acc[q];
        }
        return;
    }
    int i = blockIdx.x * 256 + threadIdx.x;
    {
        int row = i >> 8, col = i & 255;
        int nt = row >> 4, lcr = row & 15;
        int kt = col >> 5, lg = (col >> 3) & 3, j = col & 7;
        wqs[(size_t)(((nt * 8 + kt) * 64) + lg * 16 + lcr) * 8 + j] = f2bf(qw[i]);
    }
    if (i < 256 * 256) {
        int row = i >> 8, col = i & 255;
        int gs = row >> 4, lcr = row & 15;
        int h = col >> 5, lg = (col >> 3) & 3, j = col & 7;
        wps[(size_t)(((gs * 8 + h) * 64) + lg * 16 + lcr) * 8 + j] = f2bf(pw[i]);
    }
}

// ---------------- kernel A: qkv + attention ----------------
// R17 structure; CHANGE: both heads' QK^T front-end (q-norms, Bk loads,
// QK MFMAs, k-norms) computed INTERLEAVED (pacc0/pacc1 in AGPRs), then the
// two softmax/PV tails run sequentially with named locals (no runtime
// indexing). PW alias + coalesced frag-linear AO store unchanged.

__global__ void __launch_bounds__(256, 5)
fused_win_attn(const float* __restrict__ x,
               const float* __restrict__ qkv_b,
               const short* __restrict__ wqs,
               const float* __restrict__ biasT,
               const float* __restrict__ scT,
               float* out)
{
    __shared__ short SH[13824];   // QGF/PW@0  KGF@4608  VTF@9216  (8 frags each)

    const int tid = threadIdx.x;
    const int w  = tid >> 6;
    const int l  = tid & 63;
    const int lg = l >> 4;
    const int lc = l & 15;
    const int li4 = lg * 4;
    const int blk = blockIdx.x;
    const int klb = KL(l) * 8;             // read offset inside a frag (shorts)

    short* QGF = SH;                       // q-slots; wave w owns (·,w)
    short* KGF = SH + 4608;
    short* VTF = SH + 9216;

    short* ao = (short*)(out + (size_t)blk * (LTOK * CDIM) + 8192);  // frag-linear AO

    // ---- x rows w*16+lc -> 8 register A-frags ----
    short8 xf[8];
    {
        const float* xr = x + (size_t)blk * (LTOK * CDIM) + (size_t)(w * 16 + lc) * CDIM + lg * 8;
        #pragma unroll
        for (int kt = 0; kt < 8; ++kt) {
            f32x4 a = *(const f32x4*)(xr + kt * 32);
            f32x4 b = *(const f32x4*)(xr + kt * 32 + 4);
            short8 t;
            t[0]=f2bf(a[0]); t[1]=f2bf(a[1]); t[2]=f2bf(a[2]); t[3]=f2bf(a[3]);
            t[4]=f2bf(b[0]); t[5]=f2bf(b[1]); t[6]=f2bf(b[2]); t[7]=f2bf(b[3]);
            xf[kt] = t;
        }
    }
    const f32x4 fzero = {0.f, 0.f, 0.f, 0.f};
    short8 ones;
    #pragma unroll
    for (int j = 0; j < 8; ++j) ones[j] = (short)0x3F80;   // bf16 1.0

    #pragma unroll 1
    for (int g = 0; g < 4; ++g) {
        // ======== qkv: mt=w, strips 0..11 in pairs ========
        #pragma unroll
        for (int sg = 0; sg < 6; ++sg) {
            const int st0 = sg * 2, st1 = sg * 2 + 1;
            const int gnt0 = (st0 >> 2) * 16 + g * 4 + (st0 & 3);
            const int gnt1 = (st1 >> 2) * 16 + g * 4 + (st1 & 3);
            const short* wb0 = wqs + ((size_t)(gnt0 * 8) * 64 + l) * 8;
            const short* wb1 = wqs + ((size_t)(gnt1 * 8) * 64 + l) * 8;
            f32x4 a0 = fzero, a1 = fzero;
            #pragma unroll
            for (int kt = 0; kt < 8; ++kt) {
                short8 Bf0 = *(const short8*)(wb0 + kt * 512);
                short8 Bf1 = *(const short8*)(wb1 + kt * 512);
                a0 = __builtin_amdgcn_mfma_f32_16x16x32_bf16(xf[kt], Bf0, a0, 0, 0, 0);
                a1 = __builtin_amdgcn_mfma_f32_16x16x32_bf16(xf[kt], Bf1, a1, 0, 0, 0);
            }
            #pragma unroll
            for (int e = 0; e < 2; ++e) {
                const int strip = e ? st1 : st0;
                const f32x4 av = e ? a1 : a0;
                const int s = strip >> 2, nt = strip & 3;
                const float bq = qkv_b[s * 256 + g * 64 + nt * 16 + lc];
                if (s < 2) {
                    short* base = (s ? KGF : QGF) + ((nt >> 1) * 4 + w) * FRS;
                    const int lgc = (nt & 1) * 2 + (lc >> 3);
                    #pragma unroll
                    for (int i = 0; i < 4; ++i) {
                        const int l2 = lgc * 16 + li4 + i;
                        base[KL(l2) * 8 + (lc & 7)] = f2bf(av[i] + bq);
                    }
                } else {
                    short* base = VTF + ((w >> 1) * 4 + nt) * FRS;
                    const int l2 = ((w & 1) * 2 + (lg >> 1)) * 16 + lc;
                    short4_t pk;
                    #pragma unroll
                    for (int i = 0; i < 4; ++i) pk[i] = f2bf(av[i] + bq);
                    *(short4_t*)(base + KL(l2) * 8 + (li4 & 7)) = pk;
                }
            }
        }
        __syncthreads();                   // B1: QGF/KGF/VTF ready

        // ---- preload both heads' Aq; their slots then serve as PW ----
        short8 Aq0 = *(const short8*)(QGF + (0 * 4 + w) * FRS + klb);
        short8 Aq1 = *(const short8*)(QGF + (1 * 4 + w) * FRS + klb);
        short* PW = QGF + w * FRS;         // PW(ktp) at offset ktp*4*FRS

        // ======== interleaved front-end: both heads' norms + QK^T ========
        float qn0 = 1e-24f, qn1 = 1e-24f;
        #pragma unroll
        for (int j = 0; j < 8; ++j) {
            float v0 = bf2f(Aq0[j]); qn0 = fmaf(v0, v0, qn0);
            float v1 = bf2f(Aq1[j]); qn1 = fmaf(v1, v1, qn1);
        }
        qn0 += __shfl_xor(qn0, 16); qn1 += __shfl_xor(qn1, 16);
        qn0 += __shfl_xor(qn0, 32); qn1 += __shfl_xor(qn1, 32);
        const float rq0 = rsqrtf(qn0), rq1 = rsqrtf(qn1);
        const float sc0 = scT[2 * g], sc1 = scT[2 * g + 1];
        float iq0[4], iq1[4];
        #pragma unroll
        for (int i = 0; i < 4; ++i) {
            iq0[i] = __shfl(rq0, li4 + i, 16) * sc0;
            iq1[i] = __shfl(rq1, li4 + i, 16) * sc1;
        }
        f32x4 pacc0[4], pacc1[4];
        float invk0[4], invk1[4];
        #pragma unroll
        for (int nt = 0; nt < 4; ++nt) {
            short8 Bk0 = *(const short8*)(KGF + nt * FRS + klb);
            short8 Bk1 = *(const short8*)(KGF + (4 + nt) * FRS + klb);
            pacc0[nt] = __builtin_amdgcn_mfma_f32_16x16x32_bf16(Aq0, Bk0, fzero, 0, 0, 0);
            pacc1[nt] = __builtin_amdgcn_mfma_f32_16x16x32_bf16(Aq1, Bk1, fzero, 0, 0, 0);
            float kn0 = 1e-24f, kn1 = 1e-24f;
            #pragma unroll
            for (int j = 0; j < 8; ++j) {
                float v0 = bf2f(Bk0[j]); kn0 = fmaf(v0, v0, kn0);
                float v1 = bf2f(Bk1[j]); kn1 = fmaf(v1, v1, kn1);
            }
            kn0 += __shfl_xor(kn0, 16); kn1 += __shfl_xor(kn1, 16);
            kn0 += __shfl_xor(kn0, 32); kn1 += __shfl_xor(kn1, 32);
            invk0[nt] = rsqrtf(kn0);
            invk1[nt] = rsqrtf(kn1);
        }

        // ======== tail, head 0 ========
        {
            const float* bt = biasT + (2 * g) * 127 + w * 16 + 63 - lc;
            float p[4][4];
            #pragma unroll
            for (int i = 0; i < 4; ++i)
                #pragma unroll
                for (int nt = 0; nt < 4; ++nt)
                    p[i][nt] = __expf(pacc0[nt][i] * iq0[i] * invk0[nt] + bt[li4 + i - nt * 16]);
            #pragma unroll
            for (int i = 0; i < 4; ++i)
                #pragma unroll
                for (int nt = 0; nt < 4; ++nt) {
                    const int l2 = ((nt & 1) * 2 + (lc >> 3)) * 16 + li4 + i;
                    PW[(nt >> 1) * 4 * FRS + KL(l2) * 8 + (lc & 7)] = f2bf(p[i][nt]);
                }
            f32x4 oacc[2], sacc;
            oacc[0] = fzero; oacc[1] = fzero; sacc = fzero;
            #pragma unroll
            for (int ktp = 0; ktp < 2; ++ktp) {
                short8 Ap = *(const short8*)(PW + ktp * 4 * FRS + klb);
                #pragma unroll
                for (int ndv = 0; ndv < 2; ++ndv) {
                    short8 Bv = *(const short8*)(VTF + (ktp * 4 + ndv) * FRS + klb);
                    oacc[ndv] = __builtin_amdgcn_mfma_f32_16x16x32_bf16(Ap, Bv, oacc[ndv], 0, 0, 0);
                }
                sacc = __builtin_amdgcn_mfma_f32_16x16x32_bf16(Ap, ones, sacc, 0, 0, 0);
            }
            short8 aov;
            #pragma unroll
            for (int ndv = 0; ndv < 2; ++ndv)
                #pragma unroll
                for (int i = 0; i < 4; ++i)
                    aov[ndv * 4 + i] = f2bf(oacc[ndv][i] * (1.f / sacc[i]));
            *(short8*)(ao + ((size_t)(((2 * g) * 4 + w) * 64 + l)) * 8) = aov;
        }
        // ======== tail, head 1 ========
        {
            const float* bt = biasT + (2 * g + 1) * 127 + w * 16 + 63 - lc;
            float p[4][4];
            #pragma unroll
            for (int i = 0; i < 4; ++i)
                #pragma unroll
                for (int nt = 0; nt < 4; ++nt)
                    p[i][nt] = __expf(pacc1[nt][i] * iq1[i] * invk1[nt] + bt[li4 + i - nt * 16]);
            #pragma unroll
            for (int i = 0; i < 4; ++i)
                #pragma unroll
                for (int nt = 0; nt < 4; ++nt) {
                    const int l2 = ((nt & 1) * 2 + (lc >> 3)) * 16 + li4 + i;
                    PW[(nt >> 1) * 4 * FRS + KL(l2) * 8 + (lc & 7)] = f2bf(p[i][nt]);
                }
            f32x4 oacc[2], sacc;
            oacc[0] = fzero; oacc[1] = fzero; sacc = fzero;
            #pragma unroll
            for (int ktp = 0; ktp < 2; ++ktp) {
                short8 Ap = *(const short8*)(PW + ktp * 4 * FRS + klb);
                #pragma unroll
                for (int ndv = 0; ndv < 2; ++ndv) {
                    short8 Bv = *(const short8*)(VTF + (ktp * 4 + 2 + ndv) * FRS + klb);
                    oacc[ndv] = __builtin_amdgcn_mfma_f32_16x16x32_bf16(Ap, Bv, oacc[ndv], 0, 0, 0);
                }
                sacc = __builtin_amdgcn_mfma_f32_16x16x32_bf16(Ap, ones, sacc, 0, 0, 0);
            }
            short8 aov;
            #pragma unroll
            for (int ndv = 0; ndv < 2; ++ndv)
                #pragma unroll
                for (int i = 0; i < 4; ++i)
                    aov[ndv * 4 + i] = f2bf(oacc[ndv][i] * (1.f / sacc[i]));
            *(short8*)(ao + ((size_t)(((2 * g + 1) * 4 + w) * 64 + l)) * 8) = aov;
        }
        __syncthreads();                   // B2: cross-wave KGF/VTF reads done before next-g writes
    }
}

// ---------------- kernel B: proj GEMM per window ----------------
// kt-split staging: heads 0-3 staged (16 frags, 18432 B LDS), MFMA'd, then
// heads 4-7 re-staged into the same buffer. accP persists in AGPRs (same
// accumulation order as before). (256,5) -> 5 blocks/CU (20 waves).
__global__ void __launch_bounds__(256, 5)
proj_win(const float* __restrict__ proj_b,
         const short* __restrict__ wps,
         float* out)
{
    __shared__ short AF[16 * FRS];    // 18432 B

    const int tid = threadIdx.x;
    const int w  = tid >> 6;
    const int l  = tid & 63;
    const int lg = l >> 4;
    const int lc = l & 15;
    const int li4 = lg * 4;
    const int blk = blockIdx.x;
    const int klb = KL(l) * 8;

    const short* ao = (const short*)(out + (size_t)blk * (LTOK * CDIM) + 8192);

    f32x4 accP[4][4];
    #pragma unroll
    for (int a = 0; a < 4; ++a)
        #pragma unroll
        for (int b = 0; b < 4; ++b) accP[a][b] = (f32x4){0,0,0,0};

    #pragma unroll
    for (int ph = 0; ph < 2; ++ph) {
        if (ph) __syncthreads();               // WAR: phase-0 reads done before restage
        // ---- stage 4 frags per wave: global frag = ph*16 + w*4 + u ----
        #pragma unroll
        for (int u = 0; u < 4; ++u) {
            const int fl = w * 4 + u;          // local slot = head_local*4 + mt (head_local=w, mt=u)
            short8 t = *(const short8*)(ao + ((size_t)((ph * 16 + fl) * 64 + l)) * 8);
            #pragma unroll
            for (int j = 0; j < 8; ++j) {
                const int r = lg * 4 + (j & 3);
                const int c = (j >> 2) * 16 + lc;
                AF[fl * FRS + KL((c >> 3) * 16 + r) * 8 + (c & 7)] = t[j];
            }
        }
        __syncthreads();
        // ---- MFMA over this phase's 4 heads ----
        #pragma unroll
        for (int kt2 = 0; kt2 < 4; ++kt2) {
            short8 Aa0 = *(const short8*)(AF + (kt2 * 4 + 0) * FRS + klb);
            short8 Aa1 = *(const short8*)(AF + (kt2 * 4 + 1) * FRS + klb);
            short8 Aa2 = *(const short8*)(AF + (kt2 * 4 + 2) * FRS + klb);
            short8 Aa3 = *(const short8*)(AF + (kt2 * 4 + 3) * FRS + klb);
            const int kt = ph * 4 + kt2;
            #pragma unroll
            for (int ntl = 0; ntl < 4; ++ntl) {
                short8 Bp = *(const short8*)(wps + ((size_t)((w * 4 + ntl) * 8 + kt) * 64 + l) * 8);
                accP[0][ntl] = __builtin_amdgcn_mfma_f32_16x16x32_bf16(Aa0, Bp, accP[0][ntl], 0, 0, 0);
                accP[1][ntl] = __builtin_amdgcn_mfma_f32_16x16x32_bf16(Aa1, Bp, accP[1][ntl], 0, 0, 0);
                accP[2][ntl] = __builtin_amdgcn_mfma_f32_16x16x32_bf16(Aa2, Bp, accP[2][ntl], 0, 0, 0);
                accP[3][ntl] = __builtin_amdgcn_mfma_f32_16x16x32_bf16(Aa3, Bp, accP[3][ntl], 0, 0, 0);
            }
        }
    }

    // ---- epilogue: out = accP + proj_b (overwrites AO region too) ----
    float* ob = out + (size_t)blk * (LTOK * CDIM);
    #pragma unroll
    for (int ntl = 0; ntl < 4; ++ntl) {
        const float pb = proj_b[w * 64 + ntl * 16 + lc];
        #pragma unroll
        for (int mt = 0; mt < 4; ++mt)
            #pragma unroll
            for (int i = 0; i < 4; ++i)
                ob[(size_t)(mt * 16 + li4 + i) * 256 + w * 64 + ntl * 16 + lc] = accP[mt][ntl][i] + pb;
    }
}

extern "C" void kernel_launch(void* const* d_in, const int* in_sizes, int n_in,
                              void* d_out, int out_size, void* d_ws, size_t ws_size,
                              hipStream_t stream) {
    const float* x     = (const float*)d_in[0];
    const float* qkvw  = (const float*)d_in[1];
    const float* qkvb  = (const float*)d_in[2];
    const float* projw = (const float*)d_in[3];
    const float* projb = (const float*)d_in[4];
    const float* lsc   = (const float*)d_in[5];
    const float* w1    = (const float*)d_in[6];
    const float* b1    = (const float*)d_in[7];
    const float* w2    = (const float*)d_in[8];
    const float* b2    = (const float*)d_in[9];
    float* out = (float*)d_out;

    // workspace layout
    short* wqs   = (short*)d_ws;                          // 393216 B
    short* wps   = (short*)((char*)d_ws + 393216);        // 131072 B
    float* biasT = (float*)((char*)d_ws + 524288);        // 4096 B
    float* scT   = (float*)((char*)d_ws + 528384);        // 32 B

    const int nwin = in_sizes[0] / (LTOK * CDIM);         // 4096

    prep_all<<<769, 256, 0, stream>>>(qkvw, projw, w1, b1, w2, b2, lsc, wqs, wps, biasT, scT);
    fused_win_attn<<<nwin, 256, 0, stream>>>(x, qkvb, wqs, biasT, scT, out);
    proj_win<<<nwin, 256, 0, stream>>>(projb, wps, out);
}

// Round 19
// 505.716 us; speedup vs baseline: 1.5966x; 1.5966x over previous
//
#include <hip/hip_runtime.h>
#include <hip/hip_bf16.h>

typedef __attribute__((ext_vector_type(4))) float f32x4;
typedef __attribute__((ext_vector_type(8))) short short8;
typedef __attribute__((ext_vector_type(4))) short short4_t;

#define LTOK 64
#define CDIM 256
#define FRS 576            // padded frag stride (shorts): 72 blocks x 8

static __device__ __forceinline__ short f2bf(float f) {
    __hip_bfloat16 h = __float2bfloat16(f);
    union { __hip_bfloat16 b; short s; } u; u.b = h;
    return u.s;
}
static __device__ __forceinline__ float bf2f(short s) {
    union { unsigned u; float f; } v;
    v.u = ((unsigned)(unsigned short)s) << 16;
    return v.f;
}
static __device__ __forceinline__ int KL(int l) { return l + (l >> 3); }

// ---------------- merged prep kernel ----------------
// blocks 0..767: weight bf16 conversion + fragment swizzle.
// block 768: bias table + logit scales (hides under the weight blocks).
__global__ void prep_all(const float* __restrict__ qw, const float* __restrict__ pw,
                         const float* __restrict__ w1, const float* __restrict__ b1,
                         const float* __restrict__ w2, const float* __restrict__ b2,
                         const float* __restrict__ lsc,
                         short* __restrict__ wqs, short* __restrict__ wps,
                         float* __restrict__ biasT, float* __restrict__ scT) {
    if (blockIdx.x == 768) {
        int t = threadIdx.x;
        if (t < 8) scT[t] = expf(fminf(lsc[t], logf(100.0f)));
        if (t < 127) {
            float delta = (float)(t - 63);
            float sg = (delta > 0.f) ? 1.f : ((delta < 0.f) ? -1.f : 0.f);
            float r = sg * log1pf(fabsf(delta));
            float acc[8];
            #pragma unroll
            for (int q = 0; q < 8; ++q) acc[q] = b2[q];
            for (int m = 0; m < 384; ++m) {
                float hid = fmaxf(fmaf(r, w1[m * 2 + 1], b1[m]), 0.f);
                #pragma unroll
                for (int q = 0; q < 8; ++q) acc[q] = fmaf(hid, w2[q * 384 + m], acc[q]);
            }
            #pragma unroll
            for (int q = 0; q < 8; ++q) biasT[q * 127 + t] = acc[q];
        }
        return;
    }
    int i = blockIdx.x * 256 + threadIdx.x;
    {
        int row = i >> 8, col = i & 255;
        int nt = row >> 4, lcr = row & 15;
        int kt = col >> 5, lg = (col >> 3) & 3, j = col & 7;
        wqs[(size_t)(((nt * 8 + kt) * 64) + lg * 16 + lcr) * 8 + j] = f2bf(qw[i]);
    }
    if (i < 256 * 256) {
        int row = i >> 8, col = i & 255;
        int gs = row >> 4, lcr = row & 15;
        int h = col >> 5, lg = (col >> 3) & 3, j = col & 7;
        wps[(size_t)(((gs * 8 + h) * 64) + lg * 16 + lcr) * 8 + j] = f2bf(pw[i]);
    }
}

// ---------------- kernel A: qkv + attention ----------------
// R15 attention structure (frag norms, no-max exp, ones-MFMA rowsums, PW
// aliased on QGF q-slots, LDS 27648 B, (256,5) -> 5 blocks/CU) with the
// coalesced frag-linear AO store (C-layout short8, one 1KB wave store per
// head). Sequential heads — interleaving them spills (R18). 2 barriers/g.

__global__ void __launch_bounds__(256, 5)
fused_win_attn(const float* __restrict__ x,
               const float* __restrict__ qkv_b,
               const short* __restrict__ wqs,
               const float* __restrict__ biasT,
               const float* __restrict__ scT,
               float* out)
{
    __shared__ short SH[13824];   // QGF/PW@0  KGF@4608  VTF@9216  (8 frags each)

    const int tid = threadIdx.x;
    const int w  = tid >> 6;
    const int l  = tid & 63;
    const int lg = l >> 4;
    const int lc = l & 15;
    const int li4 = lg * 4;
    const int blk = blockIdx.x;
    const int klb = KL(l) * 8;             // read offset inside a frag (shorts)

    short* QGF = SH;                       // q-slots; wave w owns (·,w)
    short* KGF = SH + 4608;
    short* VTF = SH + 9216;

    short* ao = (short*)(out + (size_t)blk * (LTOK * CDIM) + 8192);  // frag-linear AO

    // ---- x rows w*16+lc -> 8 register A-frags ----
    short8 xf[8];
    {
        const float* xr = x + (size_t)blk * (LTOK * CDIM) + (size_t)(w * 16 + lc) * CDIM + lg * 8;
        #pragma unroll
        for (int kt = 0; kt < 8; ++kt) {
            f32x4 a = *(const f32x4*)(xr + kt * 32);
            f32x4 b = *(const f32x4*)(xr + kt * 32 + 4);
            short8 t;
            t[0]=f2bf(a[0]); t[1]=f2bf(a[1]); t[2]=f2bf(a[2]); t[3]=f2bf(a[3]);
            t[4]=f2bf(b[0]); t[5]=f2bf(b[1]); t[6]=f2bf(b[2]); t[7]=f2bf(b[3]);
            xf[kt] = t;
        }
    }
    const f32x4 fzero = {0.f, 0.f, 0.f, 0.f};
    short8 ones;
    #pragma unroll
    for (int j = 0; j < 8; ++j) ones[j] = (short)0x3F80;   // bf16 1.0

    #pragma unroll 1
    for (int g = 0; g < 4; ++g) {
        // ======== qkv: mt=w, strips 0..11 in pairs ========
        #pragma unroll
        for (int sg = 0; sg < 6; ++sg) {
            const int st0 = sg * 2, st1 = sg * 2 + 1;
            const int gnt0 = (st0 >> 2) * 16 + g * 4 + (st0 & 3);
            const int gnt1 = (st1 >> 2) * 16 + g * 4 + (st1 & 3);
            const short* wb0 = wqs + ((size_t)(gnt0 * 8) * 64 + l) * 8;
            const short* wb1 = wqs + ((size_t)(gnt1 * 8) * 64 + l) * 8;
            f32x4 a0 = fzero, a1 = fzero;
            #pragma unroll
            for (int kt = 0; kt < 8; ++kt) {
                short8 Bf0 = *(const short8*)(wb0 + kt * 512);
                short8 Bf1 = *(const short8*)(wb1 + kt * 512);
                a0 = __builtin_amdgcn_mfma_f32_16x16x32_bf16(xf[kt], Bf0, a0, 0, 0, 0);
                a1 = __builtin_amdgcn_mfma_f32_16x16x32_bf16(xf[kt], Bf1, a1, 0, 0, 0);
            }
            #pragma unroll
            for (int e = 0; e < 2; ++e) {
                const int strip = e ? st1 : st0;
                const f32x4 av = e ? a1 : a0;
                const int s = strip >> 2, nt = strip & 3;
                const float bq = qkv_b[s * 256 + g * 64 + nt * 16 + lc];
                if (s < 2) {
                    short* base = (s ? KGF : QGF) + ((nt >> 1) * 4 + w) * FRS;
                    const int lgc = (nt & 1) * 2 + (lc >> 3);
                    #pragma unroll
                    for (int i = 0; i < 4; ++i) {
                        const int l2 = lgc * 16 + li4 + i;
                        base[KL(l2) * 8 + (lc & 7)] = f2bf(av[i] + bq);
                    }
                } else {
                    short* base = VTF + ((w >> 1) * 4 + nt) * FRS;
                    const int l2 = ((w & 1) * 2 + (lg >> 1)) * 16 + lc;
                    short4_t pk;
                    #pragma unroll
                    for (int i = 0; i < 4; ++i) pk[i] = f2bf(av[i] + bq);
                    *(short4_t*)(base + KL(l2) * 8 + (li4 & 7)) = pk;
                }
            }
        }
        __syncthreads();                   // B1: QGF/KGF/VTF ready

        // ---- preload both heads' Aq; their slots then serve as PW ----
        short8 Aq0 = *(const short8*)(QGF + (0 * 4 + w) * FRS + klb);
        short8 Aq1 = *(const short8*)(QGF + (1 * 4 + w) * FRS + klb);
        short* PW = QGF + w * FRS;         // PW(ktp) at offset ktp*4*FRS

        // ======== attention: wave = rows w*16..+15, both heads sequential ========
        #pragma unroll 1
        for (int hh = 0; hh < 2; ++hh) {
            const int h = 2 * g + hh;
            const float sc = scT[h];
            const short8 Aq = hh ? Aq1 : Aq0;
            float qn = 1e-24f;
            #pragma unroll
            for (int j = 0; j < 8; ++j) { float v = bf2f(Aq[j]); qn = fmaf(v, v, qn); }
            qn += __shfl_xor(qn, 16);
            qn += __shfl_xor(qn, 32);
            const float rq = rsqrtf(qn);
            f32x4 pacc[4];
            float invk[4];
            #pragma unroll
            for (int nt = 0; nt < 4; ++nt) {
                short8 Bk = *(const short8*)(KGF + (hh * 4 + nt) * FRS + klb);
                pacc[nt] = __builtin_amdgcn_mfma_f32_16x16x32_bf16(Aq, Bk, fzero, 0, 0, 0);
                float kn = 1e-24f;
                #pragma unroll
                for (int j = 0; j < 8; ++j) { float v = bf2f(Bk[j]); kn = fmaf(v, v, kn); }
                kn += __shfl_xor(kn, 16);
                kn += __shfl_xor(kn, 32);
                invk[nt] = rsqrtf(kn);
            }
            float iq[4];
            #pragma unroll
            for (int i = 0; i < 4; ++i) iq[i] = __shfl(rq, li4 + i, 16) * sc;
            const float* bt = biasT + h * 127 + w * 16 + 63 - lc;
            float p[4][4];
            #pragma unroll
            for (int i = 0; i < 4; ++i)
                #pragma unroll
                for (int nt = 0; nt < 4; ++nt)
                    p[i][nt] = __expf(pacc[nt][i] * iq[i] * invk[nt] + bt[li4 + i - nt * 16]);
            #pragma unroll
            for (int i = 0; i < 4; ++i)
                #pragma unroll
                for (int nt = 0; nt < 4; ++nt) {
                    const int l2 = ((nt & 1) * 2 + (lc >> 3)) * 16 + li4 + i;
                    PW[(nt >> 1) * 4 * FRS + KL(l2) * 8 + (lc & 7)] = f2bf(p[i][nt]);
                }
            f32x4 oacc[2], sacc;
            oacc[0] = fzero; oacc[1] = fzero; sacc = fzero;
            #pragma unroll
            for (int ktp = 0; ktp < 2; ++ktp) {
                short8 Ap = *(const short8*)(PW + ktp * 4 * FRS + klb);
                #pragma unroll
                for (int ndv = 0; ndv < 2; ++ndv) {
                    short8 Bv = *(const short8*)(VTF + (ktp * 4 + hh * 2 + ndv) * FRS + klb);
                    oacc[ndv] = __builtin_amdgcn_mfma_f32_16x16x32_bf16(Ap, Bv, oacc[ndv], 0, 0, 0);
                }
                sacc = __builtin_amdgcn_mfma_f32_16x16x32_bf16(Ap, ones, sacc, 0, 0, 0);
            }
            // ---- pack normalized AO (C-layout) + coalesced frag-linear store ----
            short8 aov;
            #pragma unroll
            for (int ndv = 0; ndv < 2; ++ndv)
                #pragma unroll
                for (int i = 0; i < 4; ++i)
                    aov[ndv * 4 + i] = f2bf(oacc[ndv][i] * (1.f / sacc[i]));
            *(short8*)(ao + ((size_t)((h * 4 + w) * 64 + l)) * 8) = aov;
        }
        __syncthreads();                   // B2: cross-wave KGF/VTF reads done before next-g writes
    }
}

// ---------------- kernel B: proj GEMM per window ----------------
// AO arrives frag-linear in C-layout: staging load is a coalesced 16B/lane
// read; the C->A-frag transpose happens in the LDS scatter (KL-padded).
// (256,4): accP needs 64 AGPRs — (256,5) spills it (R18).
__global__ void __launch_bounds__(256, 4)
proj_win(const float* __restrict__ proj_b,
         const short* __restrict__ wps,
         float* out)
{
    __shared__ short AF[32 * FRS];    // 36864 B

    const int tid = threadIdx.x;
    const int w  = tid >> 6;
    const int l  = tid & 63;
    const int lg = l >> 4;
    const int lc = l & 15;
    const int li4 = lg * 4;
    const int blk = blockIdx.x;
    const int klb = KL(l) * 8;

    const short* ao = (const short*)(out + (size_t)blk * (LTOK * CDIM) + 8192);

    // ---- stage AO: coalesced load + C->A-frag KL-scatter ----
    #pragma unroll
    for (int u = 0; u < 8; ++u) {
        const int f = w * 8 + u;                   // f = h*4 + mt
        short8 t = *(const short8*)(ao + ((size_t)(f * 64 + l)) * 8);
        #pragma unroll
        for (int j = 0; j < 8; ++j) {
            const int r = lg * 4 + (j & 3);        // row within 16
            const int c = (j >> 2) * 16 + lc;      // col within 32
            AF[f * FRS + KL((c >> 3) * 16 + r) * 8 + (c & 7)] = t[j];
        }
    }
    __syncthreads();

    f32x4 accP[4][4];
    #pragma unroll
    for (int a = 0; a < 4; ++a)
        #pragma unroll
        for (int b = 0; b < 4; ++b) accP[a][b] = (f32x4){0,0,0,0};

    #pragma unroll
    for (int kt = 0; kt < 8; ++kt) {
        short8 Aa0 = *(const short8*)(AF + (kt * 4 + 0) * FRS + klb);
        short8 Aa1 = *(const short8*)(AF + (kt * 4 + 1) * FRS + klb);
        short8 Aa2 = *(const short8*)(AF + (kt * 4 + 2) * FRS + klb);
        short8 Aa3 = *(const short8*)(AF + (kt * 4 + 3) * FRS + klb);
        #pragma unroll
        for (int ntl = 0; ntl < 4; ++ntl) {
            short8 Bp = *(const short8*)(wps + ((size_t)((w * 4 + ntl) * 8 + kt) * 64 + l) * 8);
            accP[0][ntl] = __builtin_amdgcn_mfma_f32_16x16x32_bf16(Aa0, Bp, accP[0][ntl], 0, 0, 0);
            accP[1][ntl] = __builtin_amdgcn_mfma_f32_16x16x32_bf16(Aa1, Bp, accP[1][ntl], 0, 0, 0);
            accP[2][ntl] = __builtin_amdgcn_mfma_f32_16x16x32_bf16(Aa2, Bp, accP[2][ntl], 0, 0, 0);
            accP[3][ntl] = __builtin_amdgcn_mfma_f32_16x16x32_bf16(Aa3, Bp, accP[3][ntl], 0, 0, 0);
        }
    }

    // ---- epilogue: out = accP + proj_b (overwrites AO region too) ----
    float* ob = out + (size_t)blk * (LTOK * CDIM);
    #pragma unroll
    for (int ntl = 0; ntl < 4; ++ntl) {
        const float pb = proj_b[w * 64 + ntl * 16 + lc];
        #pragma unroll
        for (int mt = 0; mt < 4; ++mt)
            #pragma unroll
            for (int i = 0; i < 4; ++i)
                ob[(size_t)(mt * 16 + li4 + i) * 256 + w * 64 + ntl * 16 + lc] = accP[mt][ntl][i] + pb;
    }
}

extern "C" void kernel_launch(void* const* d_in, const int* in_sizes, int n_in,
                              void* d_out, int out_size, void* d_ws, size_t ws_size,
                              hipStream_t stream) {
    const float* x     = (const float*)d_in[0];
    const float* qkvw  = (const float*)d_in[1];
    const float* qkvb  = (const float*)d_in[2];
    const float* projw = (const float*)d_in[3];
    const float* projb = (const float*)d_in[4];
    const float* lsc   = (const float*)d_in[5];
    const float* w1    = (const float*)d_in[6];
    const float* b1    = (const float*)d_in[7];
    const float* w2    = (const float*)d_in[8];
    const float* b2    = (const float*)d_in[9];
    float* out = (float*)d_out;

    // workspace layout
    short* wqs   = (short*)d_ws;                          // 393216 B
    short* wps   = (short*)((char*)d_ws + 393216);        // 131072 B
    float* biasT = (float*)((char*)d_ws + 524288);        // 4096 B
    float* scT   = (float*)((char*)d_ws + 528384);        // 32 B

    const int nwin = in_sizes[0] / (LTOK * CDIM);         // 4096

    prep_all<<<769, 256, 0, stream>>>(qkvw, projw, w1, b1, w2, b2, lsc, wqs, wps, biasT, scT);
    fused_win_attn<<<nwin, 256, 0, stream>>>(x, qkvb, wqs, biasT, scT, out);
    proj_win<<<nwin, 256, 0, stream>>>(projb, wps, out);
}

// Round 20
// 471.249 us; speedup vs baseline: 1.7134x; 1.0731x over previous
//
#include <hip/hip_runtime.h>
#include <hip/hip_bf16.h>

typedef __attribute__((ext_vector_type(4))) float f32x4;
typedef __attribute__((ext_vector_type(8))) short short8;
typedef __attribute__((ext_vector_type(4))) short short4_t;

#define LTOK 64
#define CDIM 256
#define FRS 576            // padded frag stride (shorts): 72 blocks x 8

static __device__ __forceinline__ short f2bf(float f) {
    __hip_bfloat16 h = __float2bfloat16(f);
    union { __hip_bfloat16 b; short s; } u; u.b = h;
    return u.s;
}
static __device__ __forceinline__ float bf2f(short s) {
    union { unsigned u; float f; } v;
    v.u = ((unsigned)(unsigned short)s) << 16;
    return v.f;
}
static __device__ __forceinline__ int KL(int l) { return l + (l >> 3); }

// ---------------- merged prep kernel ----------------
__global__ void prep_all(const float* __restrict__ qw, const float* __restrict__ pw,
                         const float* __restrict__ w1, const float* __restrict__ b1,
                         const float* __restrict__ w2, const float* __restrict__ b2,
                         const float* __restrict__ lsc,
                         short* __restrict__ wqs, short* __restrict__ wps,
                         float* __restrict__ biasT, float* __restrict__ scT) {
    if (blockIdx.x == 768) {
        int t = threadIdx.x;
        if (t < 8) scT[t] = expf(fminf(lsc[t], logf(100.0f)));
        if (t < 127) {
            float delta = (float)(t - 63);
            float sg = (delta > 0.f) ? 1.f : ((delta < 0.f) ? -1.f : 0.f);
            float r = sg * log1pf(fabsf(delta));
            float acc[8];
            #pragma unroll
            for (int q = 0; q < 8; ++q) acc[q] = b2[q];
            for (int m = 0; m < 384; ++m) {
                float hid = fmaxf(fmaf(r, w1[m * 2 + 1], b1[m]), 0.f);
                #pragma unroll
                for (int q = 0; q < 8; ++q) acc[q] = fmaf(hid, w2[q * 384 + m], acc[q]);
            }
            #pragma unroll
            for (int q = 0; q < 8; ++q) biasT[q * 127 + t] = acc[q];
        }
        return;
    }
    int i = blockIdx.x * 256 + threadIdx.x;
    {
        int row = i >> 8, col = i & 255;
        int nt = row >> 4, lcr = row & 15;
        int kt = col >> 5, lg = (col >> 3) & 3, j = col & 7;
        wqs[(size_t)(((nt * 8 + kt) * 64) + lg * 16 + lcr) * 8 + j] = f2bf(qw[i]);
    }
    if (i < 256 * 256) {
        int row = i >> 8, col = i & 255;
        int gs = row >> 4, lcr = row & 15;
        int h = col >> 5, lg = (col >> 3) & 3, j = col & 7;
        wps[(size_t)(((gs * 8 + h) * 64) + lg * 16 + lcr) * 8 + j] = f2bf(pw[i]);
    }
}

// ---------------- kernel A: qkv + attention (R19/R17 verbatim) ----------------
__global__ void __launch_bounds__(256, 5)
fused_win_attn(const float* __restrict__ x,
               const float* __restrict__ qkv_b,
               const short* __restrict__ wqs,
               const float* __restrict__ biasT,
               const float* __restrict__ scT,
               float* out)
{
    __shared__ short SH[13824];   // QGF/PW@0  KGF@4608  VTF@9216  (8 frags each)

    const int tid = threadIdx.x;
    const int w  = tid >> 6;
    const int l  = tid & 63;
    const int lg = l >> 4;
    const int lc = l & 15;
    const int li4 = lg * 4;
    const int blk = blockIdx.x;
    const int klb = KL(l) * 8;             // read offset inside a frag (shorts)

    short* QGF = SH;                       // q-slots; wave w owns (·,w)
    short* KGF = SH + 4608;
    short* VTF = SH + 9216;

    short* ao = (short*)(out + (size_t)blk * (LTOK * CDIM) + 8192);  // frag-linear AO

    // ---- x rows w*16+lc -> 8 register A-frags ----
    short8 xf[8];
    {
        const float* xr = x + (size_t)blk * (LTOK * CDIM) + (size_t)(w * 16 + lc) * CDIM + lg * 8;
        #pragma unroll
        for (int kt = 0; kt < 8; ++kt) {
            f32x4 a = *(const f32x4*)(xr + kt * 32);
            f32x4 b = *(const f32x4*)(xr + kt * 32 + 4);
            short8 t;
            t[0]=f2bf(a[0]); t[1]=f2bf(a[1]); t[2]=f2bf(a[2]); t[3]=f2bf(a[3]);
            t[4]=f2bf(b[0]); t[5]=f2bf(b[1]); t[6]=f2bf(b[2]); t[7]=f2bf(b[3]);
            xf[kt] = t;
        }
    }
    const f32x4 fzero = {0.f, 0.f, 0.f, 0.f};
    short8 ones;
    #pragma unroll
    for (int j = 0; j < 8; ++j) ones[j] = (short)0x3F80;   // bf16 1.0

    #pragma unroll 1
    for (int g = 0; g < 4; ++g) {
        // ======== qkv: mt=w, strips 0..11 in pairs ========
        #pragma unroll
        for (int sg = 0; sg < 6; ++sg) {
            const int st0 = sg * 2, st1 = sg * 2 + 1;
            const int gnt0 = (st0 >> 2) * 16 + g * 4 + (st0 & 3);
            const int gnt1 = (st1 >> 2) * 16 + g * 4 + (st1 & 3);
            const short* wb0 = wqs + ((size_t)(gnt0 * 8) * 64 + l) * 8;
            const short* wb1 = wqs + ((size_t)(gnt1 * 8) * 64 + l) * 8;
            f32x4 a0 = fzero, a1 = fzero;
            #pragma unroll
            for (int kt = 0; kt < 8; ++kt) {
                short8 Bf0 = *(const short8*)(wb0 + kt * 512);
                short8 Bf1 = *(const short8*)(wb1 + kt * 512);
                a0 = __builtin_amdgcn_mfma_f32_16x16x32_bf16(xf[kt], Bf0, a0, 0, 0, 0);
                a1 = __builtin_amdgcn_mfma_f32_16x16x32_bf16(xf[kt], Bf1, a1, 0, 0, 0);
            }
            #pragma unroll
            for (int e = 0; e < 2; ++e) {
                const int strip = e ? st1 : st0;
                const f32x4 av = e ? a1 : a0;
                const int s = strip >> 2, nt = strip & 3;
                const float bq = qkv_b[s * 256 + g * 64 + nt * 16 + lc];
                if (s < 2) {
                    short* base = (s ? KGF : QGF) + ((nt >> 1) * 4 + w) * FRS;
                    const int lgc = (nt & 1) * 2 + (lc >> 3);
                    #pragma unroll
                    for (int i = 0; i < 4; ++i) {
                        const int l2 = lgc * 16 + li4 + i;
                        base[KL(l2) * 8 + (lc & 7)] = f2bf(av[i] + bq);
                    }
                } else {
                    short* base = VTF + ((w >> 1) * 4 + nt) * FRS;
                    const int l2 = ((w & 1) * 2 + (lg >> 1)) * 16 + lc;
                    short4_t pk;
                    #pragma unroll
                    for (int i = 0; i < 4; ++i) pk[i] = f2bf(av[i] + bq);
                    *(short4_t*)(base + KL(l2) * 8 + (li4 & 7)) = pk;
                }
            }
        }
        __syncthreads();                   // B1: QGF/KGF/VTF ready

        // ---- preload both heads' Aq; their slots then serve as PW ----
        short8 Aq0 = *(const short8*)(QGF + (0 * 4 + w) * FRS + klb);
        short8 Aq1 = *(const short8*)(QGF + (1 * 4 + w) * FRS + klb);
        short* PW = QGF + w * FRS;         // PW(ktp) at offset ktp*4*FRS

        // ======== attention: wave = rows w*16..+15, both heads sequential ========
        #pragma unroll 1
        for (int hh = 0; hh < 2; ++hh) {
            const int h = 2 * g + hh;
            const float sc = scT[h];
            const short8 Aq = hh ? Aq1 : Aq0;
            float qn = 1e-24f;
            #pragma unroll
            for (int j = 0; j < 8; ++j) { float v = bf2f(Aq[j]); qn = fmaf(v, v, qn); }
            qn += __shfl_xor(qn, 16);
            qn += __shfl_xor(qn, 32);
            const float rq = rsqrtf(qn);
            f32x4 pacc[4];
            float invk[4];
            #pragma unroll
            for (int nt = 0; nt < 4; ++nt) {
                short8 Bk = *(const short8*)(KGF + (hh * 4 + nt) * FRS + klb);
                pacc[nt] = __builtin_amdgcn_mfma_f32_16x16x32_bf16(Aq, Bk, fzero, 0, 0, 0);
                float kn = 1e-24f;
                #pragma unroll
                for (int j = 0; j < 8; ++j) { float v = bf2f(Bk[j]); kn = fmaf(v, v, kn); }
                kn += __shfl_xor(kn, 16);
                kn += __shfl_xor(kn, 32);
                invk[nt] = rsqrtf(kn);
            }
            float iq[4];
            #pragma unroll
            for (int i = 0; i < 4; ++i) iq[i] = __shfl(rq, li4 + i, 16) * sc;
            const float* bt = biasT + h * 127 + w * 16 + 63 - lc;
            float p[4][4];
            #pragma unroll
            for (int i = 0; i < 4; ++i)
                #pragma unroll
                for (int nt = 0; nt < 4; ++nt)
                    p[i][nt] = __expf(pacc[nt][i] * iq[i] * invk[nt] + bt[li4 + i - nt * 16]);
            #pragma unroll
            for (int i = 0; i < 4; ++i)
                #pragma unroll
                for (int nt = 0; nt < 4; ++nt) {
                    const int l2 = ((nt & 1) * 2 + (lc >> 3)) * 16 + li4 + i;
                    PW[(nt >> 1) * 4 * FRS + KL(l2) * 8 + (lc & 7)] = f2bf(p[i][nt]);
                }
            f32x4 oacc[2], sacc;
            oacc[0] = fzero; oacc[1] = fzero; sacc = fzero;
            #pragma unroll
            for (int ktp = 0; ktp < 2; ++ktp) {
                short8 Ap = *(const short8*)(PW + ktp * 4 * FRS + klb);
                #pragma unroll
                for (int ndv = 0; ndv < 2; ++ndv) {
                    short8 Bv = *(const short8*)(VTF + (ktp * 4 + hh * 2 + ndv) * FRS + klb);
                    oacc[ndv] = __builtin_amdgcn_mfma_f32_16x16x32_bf16(Ap, Bv, oacc[ndv], 0, 0, 0);
                }
                sacc = __builtin_amdgcn_mfma_f32_16x16x32_bf16(Ap, ones, sacc, 0, 0, 0);
            }
            // ---- pack normalized AO (C-layout) + coalesced frag-linear store ----
            short8 aov;
            #pragma unroll
            for (int ndv = 0; ndv < 2; ++ndv)
                #pragma unroll
                for (int i = 0; i < 4; ++i)
                    aov[ndv * 4 + i] = f2bf(oacc[ndv][i] * (1.f / sacc[i]));
            *(short8*)(ao + ((size_t)((h * 4 + w) * 64 + l)) * 8) = aov;
        }
        __syncthreads();                   // B2: cross-wave KGF/VTF reads done before next-g writes
    }
}

// ---------------- kernel B: proj GEMM per window (512 threads) ----------------
// 8 waves share the 32-frag AF buffer; wave w owns output cols 32w..32w+31
// (accP[4][2] = 32 AGPR/wave — halved vs 256t). 4 blocks/CU x 8 waves =
// 32 waves/CU (2x the 256t version). Staging: 4 frags per wave.
__global__ void __launch_bounds__(512, 2)
proj_win(const float* __restrict__ proj_b,
         const short* __restrict__ wps,
         float* out)
{
    __shared__ short AF[32 * FRS];    // 36864 B

    const int tid = threadIdx.x;
    const int w  = tid >> 6;          // 0..7
    const int l  = tid & 63;
    const int lg = l >> 4;
    const int lc = l & 15;
    const int li4 = lg * 4;
    const int blk = blockIdx.x;
    const int klb = KL(l) * 8;

    const short* ao = (const short*)(out + (size_t)blk * (LTOK * CDIM) + 8192);

    // ---- stage AO: coalesced load + C->A-frag KL-scatter (4 frags/wave) ----
    #pragma unroll
    for (int u = 0; u < 4; ++u) {
        const int f = w * 4 + u;                   // f = h*4 + mt
        short8 t = *(const short8*)(ao + ((size_t)(f * 64 + l)) * 8);
        #pragma unroll
        for (int j = 0; j < 8; ++j) {
            const int r = lg * 4 + (j & 3);        // row within 16
            const int c = (j >> 2) * 16 + lc;      // col within 32
            AF[f * FRS + KL((c >> 3) * 16 + r) * 8 + (c & 7)] = t[j];
        }
    }
    __syncthreads();

    f32x4 accP[4][2];
    #pragma unroll
    for (int a = 0; a < 4; ++a) { accP[a][0] = (f32x4){0,0,0,0}; accP[a][1] = (f32x4){0,0,0,0}; }

    #pragma unroll
    for (int kt = 0; kt < 8; ++kt) {
        short8 Aa0 = *(const short8*)(AF + (kt * 4 + 0) * FRS + klb);
        short8 Aa1 = *(const short8*)(AF + (kt * 4 + 1) * FRS + klb);
        short8 Aa2 = *(const short8*)(AF + (kt * 4 + 2) * FRS + klb);
        short8 Aa3 = *(const short8*)(AF + (kt * 4 + 3) * FRS + klb);
        #pragma unroll
        for (int ntl = 0; ntl < 2; ++ntl) {
            const int gs = w * 2 + ntl;            // global 16-col strip
            short8 Bp = *(const short8*)(wps + ((size_t)((gs * 8 + kt) * 64 + l)) * 8);
            accP[0][ntl] = __builtin_amdgcn_mfma_f32_16x16x32_bf16(Aa0, Bp, accP[0][ntl], 0, 0, 0);
            accP[1][ntl] = __builtin_amdgcn_mfma_f32_16x16x32_bf16(Aa1, Bp, accP[1][ntl], 0, 0, 0);
            accP[2][ntl] = __builtin_amdgcn_mfma_f32_16x16x32_bf16(Aa2, Bp, accP[2][ntl], 0, 0, 0);
            accP[3][ntl] = __builtin_amdgcn_mfma_f32_16x16x32_bf16(Aa3, Bp, accP[3][ntl], 0, 0, 0);
        }
    }

    // ---- epilogue: out = accP + proj_b (overwrites AO region too) ----
    float* ob = out + (size_t)blk * (LTOK * CDIM);
    #pragma unroll
    for (int ntl = 0; ntl < 2; ++ntl) {
        const float pb = proj_b[w * 32 + ntl * 16 + lc];
        #pragma unroll
        for (int mt = 0; mt < 4; ++mt)
            #pragma unroll
            for (int i = 0; i < 4; ++i)
                ob[(size_t)(mt * 16 + li4 + i) * 256 + w * 32 + ntl * 16 + lc] = accP[mt][ntl][i] + pb;
    }
}

extern "C" void kernel_launch(void* const* d_in, const int* in_sizes, int n_in,
                              void* d_out, int out_size, void* d_ws, size_t ws_size,
                              hipStream_t stream) {
    const float* x     = (const float*)d_in[0];
    const float* qkvw  = (const float*)d_in[1];
    const float* qkvb  = (const float*)d_in[2];
    const float* projw = (const float*)d_in[3];
    const float* projb = (const float*)d_in[4];
    const float* lsc   = (const float*)d_in[5];
    const float* w1    = (const float*)d_in[6];
    const float* b1    = (const float*)d_in[7];
    const float* w2    = (const float*)d_in[8];
    const float* b2    = (const float*)d_in[9];
    float* out = (float*)d_out;

    // workspace layout
    short* wqs   = (short*)d_ws;                          // 393216 B
    short* wps   = (short*)((char*)d_ws + 393216);        // 131072 B
    float* biasT = (float*)((char*)d_ws + 524288);        // 4096 B
    float* scT   = (float*)((char*)d_ws + 528384);        // 32 B

    const int nwin = in_sizes[0] / (LTOK * CDIM);         // 4096

    prep_all<<<769, 256, 0, stream>>>(qkvw, projw, w1, b1, w2, b2, lsc, wqs, wps, biasT, scT);
    fused_win_attn<<<nwin, 256, 0, stream>>>(x, qkvb, wqs, biasT, scT, out);
    proj_win<<<nwin, 512, 0, stream>>>(projb, wps, out);
}